// Round 5
// baseline (497.828 us; speedup 1.0000x reference)
//
#include <hip/hip_runtime.h>
#include <hip/hip_cooperative_groups.h>
#include <math.h>

namespace cg = cooperative_groups;

#define Bn 32
#define Nn 2000
#define En 32000
#define Vn 100000
#define Dn 128
#define Rn 39
#define Kn 8

#define SUBS 8
#define NPS (Nn / SUBS)   // 250 nodes per sub-block
#define NPAIR (Nn / 2)    // 1000 node pairs per graph
#define EQ (En / 4)       // 8000 edge-quads per graph
#define NR (NPS * Rn)     // 9750 LDS cells per sub-block
#define GBLK 8            // gather slabs per graph (8 blocks/graph in P3)
#define WSLOT 128         // wave-slots per graph (8 blocks x 16 waves)
#define SMEM_BYTES 73728  // max over phases: P3 red[16][9][128] floats

// Workspace layout (no aliasing):
//   [ 0)          : inv     float[B*E]          =  4,096,000
//   [ 4,096,000)  : a       float[B*N*K]        =  2,048,000
//   [ 6,144,000)  : partial float[B*9*8*128]    =  1,179,648
//
// R20: ONE cooperative mega-kernel = R17's proven interiors (140.7us) joined
// by grid.sync(). Decisive test of the aggregate kernel-boundary cost that
// R16/R18/R19 could not isolate, and -- critically -- the mega-kernel will
// finally TOP the rocprof dispatch table, exposing our counters.
//   - 256 blocks x 1024 threads; LDS 73.7KB, VGPR<=128 => 2 blocks/CU
//     capacity >= grid => cooperative launch valid.
//   - b = blk&31 in every phase: graph b pinned to XCD b%8 (R2 affinity),
//     so inv/a/partial producer->consumer stays on-XCD (G16 safety via
//     __threadfence + grid.sync at each phase edge).
//   - P1/P2: identical math to R17's cntinv/a kernels (b, sub = blk>>5).
//   - P3: R17 gather remapped to 8 blocks/graph x 16 waves (same WSLOT=128,
//     identical per-wave math), cross-wave reduce 16->1, GBLK=8 slabs.
//   - P4: blocks 0..31 run R19-style finish (reduce 8 slabs -> 9 matvecs ->
//     bias + L2-norm); finish block b is on XCD b%8 = writers' XCD.

__global__ __launch_bounds__(1024) void mega_kernel(
    const int*   __restrict__ node_ids,
    const int*   __restrict__ edge_index,
    const int*   __restrict__ edge_type,
    const float* __restrict__ emb,
    const float* __restrict__ bases,
    const float* __restrict__ comp,
    const float* __restrict__ root,
    const float* __restrict__ bias,
    float*       __restrict__ inv,
    float*       __restrict__ a,
    float*       __restrict__ partial,
    float*       __restrict__ out)
{
    cg::grid_group grid = cg::this_grid();
    __shared__ __align__(16) char smem[SMEM_BYTES];
    const int tid = threadIdx.x;
    const int blk = blockIdx.x;
    const int b = blk & 31, sub = blk >> 5;

    // ---------------- P1: cnt + inv (dst-range histogram) ----------------
    {
        int* loc = (int*)smem;                    // 39 KB
        int base = sub * NR;
        for (int i = tid; i < NR; i += 1024) loc[i] = 0;
        __syncthreads();
        const int4* dst4 = (const int4*)(edge_index + (b * 2 + 1) * En);
        const int4* et4  = (const int4*)(edge_type + b * En);
        for (int q = tid; q < EQ; q += 1024) {
            int4 d = dst4[q]; int4 t = et4[q]; int y;
            y = d.x * Rn + t.x - base; if ((unsigned)y < NR) atomicAdd(&loc[y], 1);
            y = d.y * Rn + t.y - base; if ((unsigned)y < NR) atomicAdd(&loc[y], 1);
            y = d.z * Rn + t.z - base; if ((unsigned)y < NR) atomicAdd(&loc[y], 1);
            y = d.w * Rn + t.w - base; if ((unsigned)y < NR) atomicAdd(&loc[y], 1);
        }
        __syncthreads();
        // counts -> reciprocals in place (count==0 cells never referenced)
        float* finv = (float*)loc;
        for (int i = tid; i < NR; i += 1024) {
            int c = loc[i];
            finv[i] = 1.0f / (float)c;
        }
        __syncthreads();
        float* ivb = inv + (size_t)b * En;
        for (int q = tid; q < EQ; q += 1024) {
            int4 d = dst4[q]; int4 t = et4[q];
            int e = 4 * q, y;
            y = d.x * Rn + t.x - base; if ((unsigned)y < NR) ivb[e]     = finv[y];
            y = d.y * Rn + t.y - base; if ((unsigned)y < NR) ivb[e + 1] = finv[y];
            y = d.z * Rn + t.z - base; if ((unsigned)y < NR) ivb[e + 2] = finv[y];
            y = d.w * Rn + t.w - base; if ((unsigned)y < NR) ivb[e + 3] = finv[y];
        }
    }
    __threadfence();
    grid.sync();

    // ---------------- P2: a[n][k] (src-range scatter + comp matmul) ------
    {
        float* s      = (float*)smem;             // 39 KB
        float* comp_l = (float*)(smem + NR * sizeof(float));
        int base = sub * NR;
        for (int i = tid; i < NR; i += 1024) s[i] = 0.0f;
        if (tid < Rn * Kn) comp_l[tid] = comp[tid];
        __syncthreads();
        const int4*   src4 = (const int4*)(edge_index + (b * 2 + 0) * En);
        const int4*   et4  = (const int4*)(edge_type + b * En);
        const float4* iv4  = (const float4*)(inv + (size_t)b * En);
        for (int q = tid; q < EQ; q += 1024) {
            int4 sv = src4[q]; int4 tv = et4[q]; float4 iv = iv4[q]; int y;
            y = sv.x * Rn + tv.x - base; if ((unsigned)y < NR) atomicAdd(&s[y], iv.x);
            y = sv.y * Rn + tv.y - base; if ((unsigned)y < NR) atomicAdd(&s[y], iv.y);
            y = sv.z * Rn + tv.z - base; if ((unsigned)y < NR) atomicAdd(&s[y], iv.z);
            y = sv.w * Rn + tv.w - base; if ((unsigned)y < NR) atomicAdd(&s[y], iv.w);
        }
        __syncthreads();
        float* g = a + ((size_t)b * Nn + sub * NPS) * Kn;
        for (int i = tid; i < NPS * Kn; i += 1024) {       // 2000 outputs
            int n = i >> 3, k = i & 7;
            float acc = 0.0f;
            const float* srow = &s[n * Rn];
            for (int t = 0; t < Rn; t++) acc += srow[t] * comp_l[t * Kn + k];
            g[i] = acc;
        }
    }
    __threadfence();
    grid.sync();

    // ---------------- P3: paired gather (R17 math, 16 waves/block) -------
    {
        float (*red)[9][Dn] = (float (*)[9][Dn])smem;      // [16][9][128] = 73.7 KB
        int lane = tid & 63, wv = tid >> 6;
        int Wl = sub * 16 + wv;                   // wave-slot in [0, WSLOT)
        int half = lane >> 5;                     // 0: even node, 1: odd node
        int dl = lane & 31;                       // float4 slot
        float4 acc[9];
#pragma unroll
        for (int k = 0; k < 9; k++) acc[k] = make_float4(0.f, 0.f, 0.f, 0.f);
        const int*   nb = node_ids + b * Nn;
        const float* ab = a + (size_t)b * Nn * Kn;
#pragma unroll
        for (int i0 = 0; i0 < 8; i0 += 4) {       // two batch-4 rounds
            bool   has[4];
            int    node[4];
            float4 v[4];
            float4 a0[4], a1[4];
#pragma unroll
            for (int i = 0; i < 4; i++) {
                int p = Wl + (i0 + i) * WSLOT;
                has[i] = p < NPAIR;
                node[i] = (has[i] ? 2 * p : 0) + half;
            }
#pragma unroll
            for (int i = 0; i < 4; i++) {         // 4 batched 1KB row loads
                int nid = nb[node[i]];
                v[i] = has[i] ? ((const float4*)(emb + (size_t)nid * Dn))[dl]
                              : make_float4(0.f, 0.f, 0.f, 0.f);
                const float4* ar = (const float4*)(ab + (size_t)node[i] * Kn);
                a0[i] = ar[0]; a1[i] = ar[1];
            }
#pragma unroll
            for (int i = 0; i < 4; i++) {
                float w[9] = {a0[i].x, a0[i].y, a0[i].z, a0[i].w,
                              a1[i].x, a1[i].y, a1[i].z, a1[i].w, 1.0f};
#pragma unroll
                for (int k = 0; k < 9; k++) {
                    acc[k].x += w[k] * v[i].x;
                    acc[k].y += w[k] * v[i].y;
                    acc[k].z += w[k] * v[i].z;
                    acc[k].w += w[k] * v[i].w;
                }
            }
        }
        // merge odd-node half into even half (same d-range)
#pragma unroll
        for (int k = 0; k < 9; k++) {
            acc[k].x += __shfl_down(acc[k].x, 32, 64);
            acc[k].y += __shfl_down(acc[k].y, 32, 64);
            acc[k].z += __shfl_down(acc[k].z, 32, 64);
            acc[k].w += __shfl_down(acc[k].w, 32, 64);
        }
        if (half == 0) {
#pragma unroll
            for (int k = 0; k < 9; k++)
                ((float4*)red[wv][k])[dl] = acc[k];
        }
        __syncthreads();
        // cross-wave reduce 16->1: threads 0..287 own one (k, d4) slot
        if (tid < 9 * (Dn / 4)) {
            int k = tid >> 5, d4 = tid & 31;
            float4 t = make_float4(0.f, 0.f, 0.f, 0.f);
#pragma unroll
            for (int w = 0; w < 16; w++) {
                float4 v = ((const float4*)red[w][k])[d4];
                t.x += v.x; t.y += v.y; t.z += v.z; t.w += v.w;
            }
            float4* gp = (float4*)(partial + (((size_t)b * 9 + k) * GBLK + sub) * Dn);
            gp[d4] = t;
        }
    }
    __threadfence();
    grid.sync();

    // ---------------- P4: finish (blocks 0..31 only) ----------------------
    if (blk >= Bn) return;
    {
        float*  ts   = (float*)smem;                       // [9][128] = 4.6 KB
        float4* red4 = (float4*)(smem + 4608);             // [32][32] = 16 KB
        float*  ssr  = (float*)(smem + 4608 + 16384);      // [16]
        // reduce 8 gather slabs -> ts[k][d] (coalesced along d)
        for (int slot = tid; slot < 9 * Dn; slot += 1024) {
            int k = slot >> 7, d = slot & 127;
            const float* pp = partial + (((size_t)blk * 9 + k) * GBLK) * Dn + d;
            float t = 0.0f;
#pragma unroll
            for (int c = 0; c < GBLK; c++) t += pp[c * Dn];
            ts[slot] = t;
        }
        __syncthreads();
        // 9 matvecs: 32 j-groups x 32 d4-slots, float4 along d
        int d4 = tid & 31, jg = tid >> 5;
        float4 acc = make_float4(0.f, 0.f, 0.f, 0.f);
        for (int m = 0; m < 9; m++) {
            const float4* M4 = (const float4*)((m == 8) ? root
                                                        : bases + (size_t)m * Dn * Dn);
            const float* tsm = ts + m * Dn;
#pragma unroll
            for (int jj = 0; jj < 4; jj++) {
                int j = jg * 4 + jj;
                float w = tsm[j];
                float4 mv = M4[j * 32 + d4];
                acc.x += w * mv.x; acc.y += w * mv.y;
                acc.z += w * mv.z; acc.w += w * mv.w;
            }
        }
        red4[jg * 32 + d4] = acc;
        __syncthreads();
        const float* redf = (const float*)red4;            // [32][128]
        int d = tid & 127;
        float g = (float)Nn * bias[d];
#pragma unroll
        for (int w = 0; w < 32; w++) g += redf[w * Dn + d];
        // each d duplicated 8x across 1024 threads -> scale sum-sq by 1/8
        float ss = g * g;
#pragma unroll
        for (int off = 32; off > 0; off >>= 1) ss += __shfl_down(ss, off, 64);
        if ((tid & 63) == 0) ssr[tid >> 6] = ss;
        __syncthreads();
        float tot = 0.0f;
#pragma unroll
        for (int w = 0; w < 16; w++) tot += ssr[w];
        tot *= 0.125f;
        float nrm = sqrtf(tot);
        if (tid < Dn) out[blk * Dn + tid] = g / fmaxf(nrm, 1e-5f);
    }
}

extern "C" void kernel_launch(void* const* d_in, const int* in_sizes, int n_in,
                              void* d_out, int out_size, void* d_ws, size_t ws_size,
                              hipStream_t stream) {
    const int*   node_ids   = (const int*)d_in[0];
    const int*   edge_index = (const int*)d_in[1];
    const int*   edge_type  = (const int*)d_in[2];
    const float* embedding  = (const float*)d_in[3];
    const float* bases      = (const float*)d_in[4];
    const float* comp       = (const float*)d_in[5];
    const float* root       = (const float*)d_in[6];
    const float* bias       = (const float*)d_in[7];
    float*       out        = (float*)d_out;

    char* w = (char*)d_ws;
    float* inv     = (float*)(w + 0);
    float* a       = (float*)(w + 4096000);
    float* partial = (float*)(w + 6144000);

    void* args[] = {
        (void*)&node_ids, (void*)&edge_index, (void*)&edge_type,
        (void*)&embedding, (void*)&bases, (void*)&comp, (void*)&root,
        (void*)&bias, (void*)&inv, (void*)&a, (void*)&partial, (void*)&out
    };
    hipLaunchCooperativeKernel(mega_kernel, dim3(256), dim3(1024), args, 0, stream);
}

// Round 7
// 398.183 us; speedup vs baseline: 1.2502x; 1.2502x over previous
//
#include <hip/hip_runtime.h>
#include <hip/hip_cooperative_groups.h>
#include <math.h>

namespace cg = cooperative_groups;

#define Bn 32
#define Nn 2000
#define En 32000
#define Vn 100000
#define Dn 128
#define Rn 39
#define Kn 8

#define SUBS 8            // sub-ranges per graph (P1/P2), gather blocks per graph (P3)
#define NPS (Nn / SUBS)   // 250 nodes per sub-range
#define NR (NPS * Rn)     // 9750 LDS histogram cells
#define NPAIR (Nn / 2)    // 1000 node pairs per graph
#define EQ (En / 4)       // 8000 edge-quads per graph
#define GBLK 8            // gather slabs per graph
#define WSLOT 64          // wave-slots per graph (8 blocks x 8 waves)
#define SMEM_BYTES 40960

// Workspace layout (no aliasing):
//   [ 0)          : inv     float[B*E]          =  4,096,000
//   [ 4,096,000)  : a       float[B*N*K]        =  2,048,000
//   [ 6,144,000)  : partial float[B*9*8*128]    =  1,179,648
//
// R22: decisive boundary-cost rerun, unconfounded.
//   R20 (256blk x 1024thr): VGPR capped 64 -> P3 spilled -> 396us. INVALID.
//   R21 (512blk x 512thr): needed 2 blocks/CU co-residency; launch validation
//     failed (silent no-op, absmax = max|ref|). INVALID.
//   R22: 256 blocks x 512 threads -- capacity >= 1 block/CU holds for ANY
//     register allocation (512 thr, 40KB LDS, VGPR<=512) => launch guaranteed.
//     __launch_bounds__(512,2) caps VGPR at 256: spill-impossible for P3's
//     batch-8 working set (~150 VGPR, R15-proven shape). Only 1 block/CU is
//     resident at grid 256 anyway, so the lower occupancy bound costs nothing.
//   - P1/P2: R17's K1/K2 interiors at 512 threads (NR=9750, 39KB LDS).
//   - P3: 8 waves/block, Wl in [0,64), 16 pairs/wave as 2 rounds of batch-8
//     (8KB rows in flight/wave -- ILP compensates halved TLP), shfl(+32)
//     merge, cross-wave reduce 8->1, GBLK=8 slabs.
//   - P4: blocks 0..31, R19 finish interior (512 thr), 8-slab reduce.
//   - blk = b + 32*sub: all blocks of graph b on XCD b%8 (affinity preserved);
//     __threadfence + grid.sync at phase edges (G16).
// Pre-commit: dur <= 120 => boundaries were the missing ~80us, iterate here.
//             dur >= 126 => boundary hypothesis dead; revert to R17, attack
//             interiors. Expect VGPR 130-200, WRITE_SIZE ~7.5MB (no spill).

__global__ __launch_bounds__(512, 2) void mega_kernel(
    const int*   __restrict__ node_ids,
    const int*   __restrict__ edge_index,
    const int*   __restrict__ edge_type,
    const float* __restrict__ emb,
    const float* __restrict__ bases,
    const float* __restrict__ comp,
    const float* __restrict__ root,
    const float* __restrict__ bias,
    float*       __restrict__ inv,
    float*       __restrict__ a,
    float*       __restrict__ partial,
    float*       __restrict__ out)
{
    cg::grid_group grid = cg::this_grid();
    __shared__ __align__(16) char smem[SMEM_BYTES];
    const int tid = threadIdx.x;
    const int blk = blockIdx.x;
    const int b = blk & 31, sub = blk >> 5;       // sub in [0,8)

    // ---------------- P1: cnt + inv (dst-range histogram) ----------------
    {
        int* loc = (int*)smem;                    // 39 KB
        int base = sub * NR;
        for (int i = tid; i < NR; i += 512) loc[i] = 0;
        __syncthreads();
        const int4* dst4 = (const int4*)(edge_index + (b * 2 + 1) * En);
        const int4* et4  = (const int4*)(edge_type + b * En);
        for (int q = tid; q < EQ; q += 512) {
            int4 d = dst4[q]; int4 t = et4[q]; int y;
            y = d.x * Rn + t.x - base; if ((unsigned)y < NR) atomicAdd(&loc[y], 1);
            y = d.y * Rn + t.y - base; if ((unsigned)y < NR) atomicAdd(&loc[y], 1);
            y = d.z * Rn + t.z - base; if ((unsigned)y < NR) atomicAdd(&loc[y], 1);
            y = d.w * Rn + t.w - base; if ((unsigned)y < NR) atomicAdd(&loc[y], 1);
        }
        __syncthreads();
        // counts -> reciprocals in place (count==0 cells never referenced)
        float* finv = (float*)loc;
        for (int i = tid; i < NR; i += 512) {
            int c = loc[i];
            finv[i] = 1.0f / (float)c;
        }
        __syncthreads();
        float* ivb = inv + (size_t)b * En;
        for (int q = tid; q < EQ; q += 512) {
            int4 d = dst4[q]; int4 t = et4[q];
            int e = 4 * q, y;
            y = d.x * Rn + t.x - base; if ((unsigned)y < NR) ivb[e]     = finv[y];
            y = d.y * Rn + t.y - base; if ((unsigned)y < NR) ivb[e + 1] = finv[y];
            y = d.z * Rn + t.z - base; if ((unsigned)y < NR) ivb[e + 2] = finv[y];
            y = d.w * Rn + t.w - base; if ((unsigned)y < NR) ivb[e + 3] = finv[y];
        }
    }
    __threadfence();
    grid.sync();

    // ---------------- P2: a[n][k] (src-range scatter + comp matmul) ------
    {
        float* s      = (float*)smem;             // 39 KB
        float* comp_l = (float*)(smem + 39040);   // 1.2 KB
        int base = sub * NR;
        for (int i = tid; i < NR; i += 512) s[i] = 0.0f;
        if (tid < Rn * Kn) comp_l[tid] = comp[tid];
        __syncthreads();
        const int4*   src4 = (const int4*)(edge_index + (b * 2 + 0) * En);
        const int4*   et4  = (const int4*)(edge_type + b * En);
        const float4* iv4  = (const float4*)(inv + (size_t)b * En);
        for (int q = tid; q < EQ; q += 512) {
            int4 sv = src4[q]; int4 tv = et4[q]; float4 iv = iv4[q]; int y;
            y = sv.x * Rn + tv.x - base; if ((unsigned)y < NR) atomicAdd(&s[y], iv.x);
            y = sv.y * Rn + tv.y - base; if ((unsigned)y < NR) atomicAdd(&s[y], iv.y);
            y = sv.z * Rn + tv.z - base; if ((unsigned)y < NR) atomicAdd(&s[y], iv.z);
            y = sv.w * Rn + tv.w - base; if ((unsigned)y < NR) atomicAdd(&s[y], iv.w);
        }
        __syncthreads();
        float* g = a + ((size_t)b * Nn + sub * NPS) * Kn;
        for (int i = tid; i < NPS * Kn; i += 512) {        // 2000 outputs
            int n = i >> 3, k = i & 7;
            float acc = 0.0f;
            const float* srow = &s[n * Rn];
            for (int t = 0; t < Rn; t++) acc += srow[t] * comp_l[t * Kn + k];
            g[i] = acc;
        }
    }
    __threadfence();
    grid.sync();

    // ---------------- P3: paired gather (8 waves, 16 pairs/wave) ----------
    {
        float (*red)[9][Dn] = (float (*)[9][Dn])smem;      // [8][9][128] = 36.9 KB
        int lane = tid & 63, wv = tid >> 6;
        int Wl = sub * 8 + wv;                    // wave-slot in [0, 64)
        int half = lane >> 5;                     // 0: even node, 1: odd node
        int dl = lane & 31;                       // float4 slot
        float4 acc[9];
#pragma unroll
        for (int k = 0; k < 9; k++) acc[k] = make_float4(0.f, 0.f, 0.f, 0.f);
        const int*   nb = node_ids + b * Nn;
        const float* ab = a + (size_t)b * Nn * Kn;
#pragma unroll
        for (int i0 = 0; i0 < 16; i0 += 8) {      // two batch-8 rounds
            bool   has[8];
            int    node[8];
            float4 v[8];
            float4 a0[8], a1[8];
#pragma unroll
            for (int i = 0; i < 8; i++) {
                int p = Wl + (i0 + i) * WSLOT;
                has[i] = p < NPAIR;
                node[i] = (has[i] ? 2 * p : 0) + half;
            }
#pragma unroll
            for (int i = 0; i < 8; i++) {         // 8 batched 1KB row loads
                int nid = nb[node[i]];
                v[i] = has[i] ? ((const float4*)(emb + (size_t)nid * Dn))[dl]
                              : make_float4(0.f, 0.f, 0.f, 0.f);
                const float4* ar = (const float4*)(ab + (size_t)node[i] * Kn);
                a0[i] = ar[0]; a1[i] = ar[1];
            }
#pragma unroll
            for (int i = 0; i < 8; i++) {
                float w[9] = {a0[i].x, a0[i].y, a0[i].z, a0[i].w,
                              a1[i].x, a1[i].y, a1[i].z, a1[i].w, 1.0f};
#pragma unroll
                for (int k = 0; k < 9; k++) {
                    acc[k].x += w[k] * v[i].x;
                    acc[k].y += w[k] * v[i].y;
                    acc[k].z += w[k] * v[i].z;
                    acc[k].w += w[k] * v[i].w;
                }
            }
        }
        // merge odd-node half into even half (same d-range)
#pragma unroll
        for (int k = 0; k < 9; k++) {
            acc[k].x += __shfl_down(acc[k].x, 32, 64);
            acc[k].y += __shfl_down(acc[k].y, 32, 64);
            acc[k].z += __shfl_down(acc[k].z, 32, 64);
            acc[k].w += __shfl_down(acc[k].w, 32, 64);
        }
        if (half == 0) {
#pragma unroll
            for (int k = 0; k < 9; k++)
                ((float4*)red[wv][k])[dl] = acc[k];
        }
        __syncthreads();
        // cross-wave reduce 8->1: threads 0..287 own one (k, d4) slot
        if (tid < 9 * (Dn / 4)) {
            int k = tid >> 5, d4 = tid & 31;
            float4 t = make_float4(0.f, 0.f, 0.f, 0.f);
#pragma unroll
            for (int w = 0; w < 8; w++) {
                float4 v = ((const float4*)red[w][k])[d4];
                t.x += v.x; t.y += v.y; t.z += v.z; t.w += v.w;
            }
            float4* gp = (float4*)(partial + (((size_t)b * 9 + k) * GBLK + sub) * Dn);
            gp[d4] = t;
        }
    }
    __threadfence();
    grid.sync();

    // ---------------- P4: finish (blocks 0..31 only) ----------------------
    if (blk >= Bn) return;
    {
        float*  ts   = (float*)smem;                       // [9][128] = 4.6 KB
        float4* red4 = (float4*)(smem + 4608);             // [16][32] = 8 KB
        float*  ssr  = (float*)(smem + 4608 + 8192);       // [8]
        // reduce 8 gather slabs -> ts[k][d] (coalesced along d)
        for (int slot = tid; slot < 9 * Dn; slot += 512) {
            int k = slot >> 7, d = slot & 127;
            const float* pp = partial + (((size_t)blk * 9 + k) * GBLK) * Dn + d;
            float t = 0.0f;
#pragma unroll
            for (int c = 0; c < GBLK; c++) t += pp[c * Dn];
            ts[slot] = t;
        }
        __syncthreads();
        // 9 matvecs: 16 j-groups x 32 d4-slots, float4 along d
        int d4 = tid & 31, jg = tid >> 5;
        float4 acc = make_float4(0.f, 0.f, 0.f, 0.f);
        for (int m = 0; m < 9; m++) {
            const float4* M4 = (const float4*)((m == 8) ? root
                                                        : bases + (size_t)m * Dn * Dn);
            const float* tsm = ts + m * Dn;
#pragma unroll
            for (int jj = 0; jj < 8; jj++) {
                int j = jg * 8 + jj;
                float w = tsm[j];
                float4 mv = M4[j * 32 + d4];
                acc.x += w * mv.x; acc.y += w * mv.y;
                acc.z += w * mv.z; acc.w += w * mv.w;
            }
        }
        red4[jg * 32 + d4] = acc;
        __syncthreads();
        const float* redf = (const float*)red4;            // [16][128]
        int d = tid & 127;
        float g = (float)Nn * bias[d];
#pragma unroll
        for (int w = 0; w < 16; w++) g += redf[w * Dn + d];
        // each d duplicated 4x across 512 threads -> scale sum-sq by 0.25
        float ss = g * g;
#pragma unroll
        for (int off = 32; off > 0; off >>= 1) ss += __shfl_down(ss, off, 64);
        if ((tid & 63) == 0) ssr[tid >> 6] = ss;
        __syncthreads();
        float tot = (ssr[0] + ssr[1] + ssr[2] + ssr[3] +
                     ssr[4] + ssr[5] + ssr[6] + ssr[7]) * 0.25f;
        float nrm = sqrtf(tot);
        if (tid < Dn) out[blk * Dn + tid] = g / fmaxf(nrm, 1e-5f);
    }
}

extern "C" void kernel_launch(void* const* d_in, const int* in_sizes, int n_in,
                              void* d_out, int out_size, void* d_ws, size_t ws_size,
                              hipStream_t stream) {
    const int*   node_ids   = (const int*)d_in[0];
    const int*   edge_index = (const int*)d_in[1];
    const int*   edge_type  = (const int*)d_in[2];
    const float* embedding  = (const float*)d_in[3];
    const float* bases      = (const float*)d_in[4];
    const float* comp       = (const float*)d_in[5];
    const float* root       = (const float*)d_in[6];
    const float* bias       = (const float*)d_in[7];
    float*       out        = (float*)d_out;

    char* w = (char*)d_ws;
    float* inv     = (float*)(w + 0);
    float* a       = (float*)(w + 4096000);
    float* partial = (float*)(w + 6144000);

    void* args[] = {
        (void*)&node_ids, (void*)&edge_index, (void*)&edge_type,
        (void*)&embedding, (void*)&bases, (void*)&comp, (void*)&root,
        (void*)&bias, (void*)&inv, (void*)&a, (void*)&partial, (void*)&out
    };
    hipLaunchCooperativeKernel(mega_kernel, dim3(256), dim3(512), args, 0, stream);
}

// Round 8
// 146.765 us; speedup vs baseline: 3.3920x; 2.7131x over previous
//
#include <hip/hip_runtime.h>
#include <math.h>

#define Bn 32
#define Nn 2000
#define En 32000
#define Vn 100000
#define Dn 128
#define Rn 39
#define Kn 8

#define SUBS 16           // sub-ranges per graph for K1/K2 (512 blocks = 2/CU)
#define NPH (Nn / SUBS)   // 125 nodes per sub-range
#define NRH (NPH * Rn)    // 4875 LDS histogram cells (19.5 KB)
#define NPAIR (Nn / 2)    // 1000 node pairs per graph
#define EQ (En / 4)       // 8000 edge-quads per graph
#define GBLK 16           // gather blocks per graph
#define WSLOT (GBLK * 8)  // 128 wave-slots per graph (8 waves/block)

// Workspace layout (no aliasing):
//   [ 0)          : inv     float[B*E]           =  4,096,000
//   [ 4,096,000)  : a       float[B*N*K]         =  2,048,000
//   [ 6,144,000)  : partial float[B*9*GBLK*128]  =  2,359,296   ([b][k][blk][d])
//   [ 8,503,296)  : gmat    float[B*9*128]       =    147,456
//
// R23 = R17 (proven 140.7us) + occupancy boosts, interiors untouched.
// R22's mega-kernel counters (VALUBusy 2.6%, HBM 1.7%, occ 23%) prove the
// pipeline is LATENCY-bound: fused phases at half thread count ran 2x slower
// => wall time ~ 1/parallelism. Inverting: grid-starved kernels pay linearly.
//   - K1/K2: SUBS 8->16: 512 blocks x 1024 thr = 2 blocks/CU = 32 waves/CU
//     (was 1 block/CU = 16 waves, grid-limited). LDS 19.5KB. Scan work
//     doubles -- R18 proved stream scans are ~free (latency-hidden).
//   - K3: unchanged (VGPR 108 caps at 16 waves/CU; 512x8 waves = exactly cap).
//   - K4: 512 threads (8 waves/block, was 4): 16-part reduce, 4-way j-split.
//   - Boundary fusion abandoned: R16 +4.3, R19 +2.8, R22 +145 (3 strikes).
// blockIdx.x = graph everywhere -> XCD affinity (R2 evidence: 9x fetch cut).

// K1: count + reciprocal by dst-range. 16 blocks/graph. Fused mad-filter:
// y = dst*39+et - sub*4875; in-range iff (unsigned)y < 4875.
__global__ __launch_bounds__(1024) void cntinv_kernel(const int* __restrict__ edge_index,
                                                      const int* __restrict__ edge_type,
                                                      float* __restrict__ inv) {
    int b = blockIdx.x, sub = blockIdx.y;
    int base = sub * NRH;
    __shared__ int loc[NRH];                      // 19.5 KB
    for (int i = threadIdx.x; i < NRH; i += 1024) loc[i] = 0;
    __syncthreads();
    const int4* dst4 = (const int4*)(edge_index + (b * 2 + 1) * En);
    const int4* et4  = (const int4*)(edge_type + b * En);
    for (int q = threadIdx.x; q < EQ; q += 1024) {
        int4 d = dst4[q]; int4 t = et4[q]; int y;
        y = d.x * Rn + t.x - base; if ((unsigned)y < NRH) atomicAdd(&loc[y], 1);
        y = d.y * Rn + t.y - base; if ((unsigned)y < NRH) atomicAdd(&loc[y], 1);
        y = d.z * Rn + t.z - base; if ((unsigned)y < NRH) atomicAdd(&loc[y], 1);
        y = d.w * Rn + t.w - base; if ((unsigned)y < NRH) atomicAdd(&loc[y], 1);
    }
    __syncthreads();
    // counts -> reciprocals in place (count==0 cells never referenced)
    float* finv = (float*)loc;
    for (int i = threadIdx.x; i < NRH; i += 1024) {
        int c = loc[i];
        finv[i] = 1.0f / (float)c;
    }
    __syncthreads();
    float* ivb = inv + (size_t)b * En;
    for (int q = threadIdx.x; q < EQ; q += 1024) {
        int4 d = dst4[q]; int4 t = et4[q];
        int e = 4 * q, y;
        y = d.x * Rn + t.x - base; if ((unsigned)y < NRH) ivb[e]     = finv[y];
        y = d.y * Rn + t.y - base; if ((unsigned)y < NRH) ivb[e + 1] = finv[y];
        y = d.z * Rn + t.z - base; if ((unsigned)y < NRH) ivb[e + 2] = finv[y];
        y = d.w * Rn + t.w - base; if ((unsigned)y < NRH) ivb[e + 3] = finv[y];
    }
}

// K2: 16 blocks/graph own src-ranges. Streaming scan, fused mad-filter, ONE
// LDS atomic/edge into s[src*39+t] (stride 39, coprime to 32 banks), then
// a[n][k] = s @ comp.
__global__ __launch_bounds__(1024) void a_kernel(const int* __restrict__ edge_index,
                                                 const int* __restrict__ edge_type,
                                                 const float* __restrict__ inv,
                                                 const float* __restrict__ comp,
                                                 float* __restrict__ a) {
    int b = blockIdx.x, sub = blockIdx.y;
    int base = sub * NRH;
    __shared__ float s[NRH];                      // 19.5 KB
    __shared__ float comp_l[Rn * Kn];
    for (int i = threadIdx.x; i < NRH; i += 1024) s[i] = 0.0f;
    if (threadIdx.x < Rn * Kn) comp_l[threadIdx.x] = comp[threadIdx.x];
    __syncthreads();
    const int4*   src4 = (const int4*)(edge_index + (b * 2 + 0) * En);
    const int4*   et4  = (const int4*)(edge_type + b * En);
    const float4* iv4  = (const float4*)(inv + (size_t)b * En);
    for (int q = threadIdx.x; q < EQ; q += 1024) {
        int4 sv = src4[q]; int4 tv = et4[q]; float4 iv = iv4[q]; int y;
        y = sv.x * Rn + tv.x - base; if ((unsigned)y < NRH) atomicAdd(&s[y], iv.x);
        y = sv.y * Rn + tv.y - base; if ((unsigned)y < NRH) atomicAdd(&s[y], iv.y);
        y = sv.z * Rn + tv.z - base; if ((unsigned)y < NRH) atomicAdd(&s[y], iv.z);
        y = sv.w * Rn + tv.w - base; if ((unsigned)y < NRH) atomicAdd(&s[y], iv.w);
    }
    __syncthreads();
    float* g = a + ((size_t)b * Nn + sub * NPH) * Kn;
    for (int i = threadIdx.x; i < NPH * Kn; i += 1024) {   // 1000 outputs
        int n = i >> 3, k = i & 7;
        float acc = 0.0f;
        const float* srow = &s[n * Rn];
        for (int t = 0; t < Rn; t++) acc += srow[t] * comp_l[t * Kn + k];
        g[i] = acc;
    }
}

// K3: paired gather, 8 waves/block, 16 blocks/graph (unchanged from R17;
// VGPR ~108 -> 16 waves/CU cap; 512 blocks x 8 waves = exactly at cap).
__global__ __launch_bounds__(512, 4) void gather_kernel(const int* __restrict__ node_ids,
                                                        const float* __restrict__ emb,
                                                        const float* __restrict__ a,
                                                        float* __restrict__ partial) {
    int b = blockIdx.x;
    int lane = threadIdx.x & 63, wv = threadIdx.x >> 6;
    int Wl = blockIdx.y * 8 + wv;                 // wave-slot in [0, WSLOT)
    int half = lane >> 5;                         // 0: even node, 1: odd node
    int dl = lane & 31;                           // float4 slot: d = 4*dl..4*dl+3
    __shared__ float red[8][9][Dn];               // 36.9 KB
    float4 acc[9];
#pragma unroll
    for (int k = 0; k < 9; k++) acc[k] = make_float4(0.f, 0.f, 0.f, 0.f);
    const int*   nb = node_ids + b * Nn;
    const float* ab = a + (size_t)b * Nn * Kn;
#pragma unroll
    for (int i0 = 0; i0 < 8; i0 += 4) {           // two batch-4 rounds
        bool   has[4];
        int    node[4];
        float4 v[4];
        float4 a0[4], a1[4];
#pragma unroll
        for (int i = 0; i < 4; i++) {
            int p = Wl + (i0 + i) * WSLOT;
            has[i] = p < NPAIR;
            node[i] = (has[i] ? 2 * p : 0) + half;
        }
#pragma unroll
        for (int i = 0; i < 4; i++) {             // 4 batched 1KB row loads
            int nid = nb[node[i]];
            v[i] = has[i] ? ((const float4*)(emb + (size_t)nid * Dn))[dl]
                          : make_float4(0.f, 0.f, 0.f, 0.f);
            const float4* ar = (const float4*)(ab + (size_t)node[i] * Kn);
            a0[i] = ar[0]; a1[i] = ar[1];
        }
#pragma unroll
        for (int i = 0; i < 4; i++) {
            float w[9] = {a0[i].x, a0[i].y, a0[i].z, a0[i].w,
                          a1[i].x, a1[i].y, a1[i].z, a1[i].w, 1.0f};
#pragma unroll
            for (int k = 0; k < 9; k++) {
                acc[k].x += w[k] * v[i].x;
                acc[k].y += w[k] * v[i].y;
                acc[k].z += w[k] * v[i].z;
                acc[k].w += w[k] * v[i].w;
            }
        }
    }
    // merge odd-node half into even half (same d-range)
#pragma unroll
    for (int k = 0; k < 9; k++) {
        acc[k].x += __shfl_down(acc[k].x, 32, 64);
        acc[k].y += __shfl_down(acc[k].y, 32, 64);
        acc[k].z += __shfl_down(acc[k].z, 32, 64);
        acc[k].w += __shfl_down(acc[k].w, 32, 64);
    }
    if (half == 0) {
#pragma unroll
        for (int k = 0; k < 9; k++)
            ((float4*)red[wv][k])[dl] = acc[k];
    }
    __syncthreads();
    // cross-wave reduce 8->1: threads 0..287 each own one (k, d4) float4 slot
    int slot = threadIdx.x;
    if (slot < 9 * (Dn / 4)) {
        int k = slot >> 5, d4 = slot & 31;
        float4 t = make_float4(0.f, 0.f, 0.f, 0.f);
#pragma unroll
        for (int w = 0; w < 8; w++) {
            float4 v = ((const float4*)red[w][k])[d4];
            t.x += v.x; t.y += v.y; t.z += v.z; t.w += v.w;
        }
        float4* gp = (float4*)(partial + (((size_t)b * 9 + k) * GBLK + blockIdx.y) * Dn);
        gp[d4] = t;
    }
}

// K4: one block per (graph, matrix m), 512 threads (8 waves, was 4).
// Reduce over 16 block-slabs: 16 parts x 32 d4-slots (1 iter). Matvec:
// 4-way j-split per d. Then write gmat.
__global__ __launch_bounds__(512) void matvec_kernel(const float* __restrict__ partial,
                                                     const float* __restrict__ root,
                                                     const float* __restrict__ bases,
                                                     float* __restrict__ gmat) {
    int b = blockIdx.x, m = blockIdx.y;
    int tid = threadIdx.x;
    __shared__ float4 ts4[Dn / 4];                // ts[128] as 32 float4
    __shared__ float tsh[16][Dn];                 // 8 KB (reduce + j-split scratch)
    int dg = tid & 31, part = tid >> 5;           // 32 d-groups x 16 parts
    const float4* p4 = (const float4*)(partial + ((size_t)b * 9 + m) * GBLK * Dn);
    {
        float4 v = p4[part * 32 + dg];            // 1 slab each, contiguous
        ((float4*)tsh[part])[dg] = v;
    }
    __syncthreads();
    if (part == 0) {
        float4 t = make_float4(0.f, 0.f, 0.f, 0.f);
#pragma unroll
        for (int r = 0; r < 16; r++) {
            float4 v = ((float4*)tsh[r])[dg];
            t.x += v.x; t.y += v.y; t.z += v.z; t.w += v.w;
        }
        ts4[dg] = t;
    }
    __syncthreads();
    const float* ts = (const float*)ts4;
    const float* M  = (m == 8) ? root : bases + (size_t)m * Dn * Dn;
    int d = tid & (Dn - 1), h = tid >> 7;         // 4-way j-split
    float g = 0.0f;
#pragma unroll 8
    for (int j = h * 32; j < h * 32 + 32; j++) g += ts[j] * M[j * Dn + d];
    __syncthreads();
    tsh[h][d] = g;
    __syncthreads();
    if (h == 0)
        gmat[((size_t)b * 9 + m) * Dn + d] = tsh[0][d] + tsh[1][d] + tsh[2][d] + tsh[3][d];
}

// K5: sum the 9 matvec outputs, add bias term, L2-normalize.
__global__ __launch_bounds__(128) void norm_kernel(const float* __restrict__ gmat,
                                                   const float* __restrict__ bias,
                                                   float* __restrict__ out) {
    int b = blockIdx.x, d = threadIdx.x;
    float g = (float)Nn * bias[d];
    const float* gb = gmat + (size_t)b * 9 * Dn + d;
#pragma unroll
    for (int m = 0; m < 9; m++) g += gb[m * Dn];
    float ss = g * g;
#pragma unroll
    for (int off = 32; off > 0; off >>= 1) ss += __shfl_down(ss, off, 64);
    __shared__ float s2[2];
    if ((threadIdx.x & 63) == 0) s2[threadIdx.x >> 6] = ss;
    __syncthreads();
    float nrm = sqrtf(s2[0] + s2[1]);
    out[b * Dn + d] = g / fmaxf(nrm, 1e-5f);
}

extern "C" void kernel_launch(void* const* d_in, const int* in_sizes, int n_in,
                              void* d_out, int out_size, void* d_ws, size_t ws_size,
                              hipStream_t stream) {
    const int*   node_ids   = (const int*)d_in[0];
    const int*   edge_index = (const int*)d_in[1];
    const int*   edge_type  = (const int*)d_in[2];
    const float* embedding  = (const float*)d_in[3];
    const float* bases      = (const float*)d_in[4];
    const float* comp       = (const float*)d_in[5];
    const float* root       = (const float*)d_in[6];
    const float* bias       = (const float*)d_in[7];
    float*       out        = (float*)d_out;

    char* w = (char*)d_ws;
    float* inv     = (float*)(w + 0);
    float* a       = (float*)(w + 4096000);
    float* partial = (float*)(w + 6144000);
    float* gmat    = (float*)(w + 8503296);

    cntinv_kernel<<<dim3(Bn, SUBS), 1024, 0, stream>>>(edge_index, edge_type, inv);
    a_kernel     <<<dim3(Bn, SUBS), 1024, 0, stream>>>(edge_index, edge_type, inv, comp, a);
    gather_kernel<<<dim3(Bn, GBLK), 512,  0, stream>>>(node_ids, embedding, a, partial);
    matvec_kernel<<<dim3(Bn, 9),    512,  0, stream>>>(partial, root, bases, gmat);
    norm_kernel  <<<Bn, 128, 0, stream>>>(gmat, bias, out);
}

// Round 9
// 142.065 us; speedup vs baseline: 3.5042x; 1.0331x over previous
//
#include <hip/hip_runtime.h>
#include <math.h>

#define Bn 32
#define Nn 2000
#define En 32000
#define Vn 100000
#define Dn 128
#define Rn 39
#define Kn 8

#define SUBS 8
#define NPS (Nn / SUBS)   // 250 nodes per sub-block
#define NPAIR (Nn / 2)    // 1000 node pairs per graph
#define EQ (En / 4)       // 8000 edge-quads per graph
#define NR (NPS * Rn)     // 9750 LDS cells per sub-block
#define GBLK 16           // gather blocks per graph
#define WSLOT (GBLK * 8)  // 128 wave-slots per graph (8 waves/block)

// Workspace layout (no aliasing):
//   [ 0)          : inv     float[B*E]           =  4,096,000
//   [ 4,096,000)  : a       float[B*N*K]         =  2,048,000
//   [ 6,144,000)  : partial float[B*9*GBLK*128]  =  2,359,296   ([b][k][blk][d])
//   [ 8,503,296)  : gmat    float[B*9*128]       =    147,456
//
// R24 = EXACT R17 revert (proven 140.7us best). Re-anchor + noise bound.
// Session ledger of priced levers (all dead unless noted):
//   - boundary fusion: R16 +4.3, R19 +2.8, R22 +145  => launches are cheap
//   - inv elimination (L2 gather or LDS preload): R18 +1.4, R19 +2.8
//   - K1/K2 occupancy via more blocks: R23 +6.1 (scan cost ~0.38us/scan,
//     refutes R18's "scans are free"; 24 scans/graph in this config ~ 9us)
//   - partial-stream shrink + gather cross-wave reduce: R17 -5.8  (KEPT)
// Structural model: ~110-113us/iter harness overhead (R22: 398 iter vs 285
// kernel) + ~30us latency-bound kernel-sum (R22 PMC: VALUBusy 2.6%, HBM
// 1.7%, MfmaUtil 0). Floor estimate ~125us; at 140.7 the residual ~15us is
// launch gaps + dependent-load latency spread over a strict 5-stage chain.
// blockIdx.x = graph everywhere -> XCD affinity (R2 evidence: 9x fetch cut).

// K1: fused cnt+inv. 8 blocks/graph own dst-ranges. Fused mad-filter:
// y = dst*39+et - sub*9750; in-range iff (unsigned)y < 9750.
// Counts converted to reciprocals ONCE in LDS (9750 rcp) so pass 2 is a
// pure lookup (no per-edge divide).
__global__ __launch_bounds__(1024) void cntinv_kernel(const int* __restrict__ edge_index,
                                                      const int* __restrict__ edge_type,
                                                      float* __restrict__ inv) {
    int b = blockIdx.x, sub = blockIdx.y;
    int base = sub * NR;
    __shared__ int loc[NR];                       // 39 KB
    for (int i = threadIdx.x; i < NR; i += 1024) loc[i] = 0;
    __syncthreads();
    const int4* dst4 = (const int4*)(edge_index + (b * 2 + 1) * En);
    const int4* et4  = (const int4*)(edge_type + b * En);
    for (int q = threadIdx.x; q < EQ; q += 1024) {
        int4 d = dst4[q]; int4 t = et4[q]; int y;
        y = d.x * Rn + t.x - base; if ((unsigned)y < NR) atomicAdd(&loc[y], 1);
        y = d.y * Rn + t.y - base; if ((unsigned)y < NR) atomicAdd(&loc[y], 1);
        y = d.z * Rn + t.z - base; if ((unsigned)y < NR) atomicAdd(&loc[y], 1);
        y = d.w * Rn + t.w - base; if ((unsigned)y < NR) atomicAdd(&loc[y], 1);
    }
    __syncthreads();
    // counts -> reciprocals in place (each thread owns cell i). count==0 cells
    // become inf but are never referenced by pass 2.
    float* finv = (float*)loc;
    for (int i = threadIdx.x; i < NR; i += 1024) {
        int c = loc[i];
        finv[i] = 1.0f / (float)c;
    }
    __syncthreads();
    float* ivb = inv + (size_t)b * En;
    for (int q = threadIdx.x; q < EQ; q += 1024) {
        int4 d = dst4[q]; int4 t = et4[q];
        int e = 4 * q, y;
        y = d.x * Rn + t.x - base; if ((unsigned)y < NR) ivb[e]     = finv[y];
        y = d.y * Rn + t.y - base; if ((unsigned)y < NR) ivb[e + 1] = finv[y];
        y = d.z * Rn + t.z - base; if ((unsigned)y < NR) ivb[e + 2] = finv[y];
        y = d.w * Rn + t.w - base; if ((unsigned)y < NR) ivb[e + 3] = finv[y];
    }
}

// K2: 8 blocks/graph own src-ranges. Streaming scan, fused mad-filter, ONE LDS
// atomic/edge into s[src*39+t] (stride 39, coprime to 32 banks), then
// a[n][k] = s @ comp.
__global__ __launch_bounds__(1024) void a_kernel(const int* __restrict__ edge_index,
                                                 const int* __restrict__ edge_type,
                                                 const float* __restrict__ inv,
                                                 const float* __restrict__ comp,
                                                 float* __restrict__ a) {
    int b = blockIdx.x, sub = blockIdx.y;
    int base = sub * NR;
    __shared__ float s[NR];                       // 39 KB
    __shared__ float comp_l[Rn * Kn];
    for (int i = threadIdx.x; i < NR; i += 1024) s[i] = 0.0f;
    if (threadIdx.x < Rn * Kn) comp_l[threadIdx.x] = comp[threadIdx.x];
    __syncthreads();
    const int4*   src4 = (const int4*)(edge_index + (b * 2 + 0) * En);
    const int4*   et4  = (const int4*)(edge_type + b * En);
    const float4* iv4  = (const float4*)(inv + (size_t)b * En);
    for (int q = threadIdx.x; q < EQ; q += 1024) {
        int4 sv = src4[q]; int4 tv = et4[q]; float4 iv = iv4[q]; int y;
        y = sv.x * Rn + tv.x - base; if ((unsigned)y < NR) atomicAdd(&s[y], iv.x);
        y = sv.y * Rn + tv.y - base; if ((unsigned)y < NR) atomicAdd(&s[y], iv.y);
        y = sv.z * Rn + tv.z - base; if ((unsigned)y < NR) atomicAdd(&s[y], iv.z);
        y = sv.w * Rn + tv.w - base; if ((unsigned)y < NR) atomicAdd(&s[y], iv.w);
    }
    __syncthreads();
    float* g = a + ((size_t)b * Nn + sub * NPS) * Kn;
    for (int i = threadIdx.x; i < NPS * Kn; i += 1024) {   // 2000 outputs
        int n = i >> 3, k = i & 7;
        float acc = 0.0f;
        const float* srow = &s[n * Rn];
        for (int t = 0; t < Rn; t++) acc += srow[t] * comp_l[t * Kn + k];
        g[i] = acc;
    }
}

// K3: paired gather, 8 waves/block, 16 blocks/graph. Wave-slot Wl in [0,128)
// owns pairs {p : p mod 128 == Wl} -> 8 pairs, processed in two batch-4
// rounds. Lanes 0-31 cover node 2p (d = 4*(lane&31)..+3 via float4), lanes
// 32-63 cover node 2p+1; halves merged by shfl(+32). Then the 8 waves reduce
// 8->1 through LDS and the block stores ONE 9x128 slab.
__global__ __launch_bounds__(512, 4) void gather_kernel(const int* __restrict__ node_ids,
                                                        const float* __restrict__ emb,
                                                        const float* __restrict__ a,
                                                        float* __restrict__ partial) {
    int b = blockIdx.x;
    int lane = threadIdx.x & 63, wv = threadIdx.x >> 6;
    int Wl = blockIdx.y * 8 + wv;                 // wave-slot in [0, WSLOT)
    int half = lane >> 5;                         // 0: even node, 1: odd node
    int dl = lane & 31;                           // float4 slot: d = 4*dl..4*dl+3
    __shared__ float red[8][9][Dn];               // 36.9 KB
    float4 acc[9];
#pragma unroll
    for (int k = 0; k < 9; k++) acc[k] = make_float4(0.f, 0.f, 0.f, 0.f);
    const int*   nb = node_ids + b * Nn;
    const float* ab = a + (size_t)b * Nn * Kn;
#pragma unroll
    for (int i0 = 0; i0 < 8; i0 += 4) {           // two batch-4 rounds
        bool   has[4];
        int    node[4];
        float4 v[4];
        float4 a0[4], a1[4];
#pragma unroll
        for (int i = 0; i < 4; i++) {
            int p = Wl + (i0 + i) * WSLOT;
            has[i] = p < NPAIR;
            node[i] = (has[i] ? 2 * p : 0) + half;
        }
#pragma unroll
        for (int i = 0; i < 4; i++) {             // 4 batched 1KB row loads
            int nid = nb[node[i]];
            v[i] = has[i] ? ((const float4*)(emb + (size_t)nid * Dn))[dl]
                          : make_float4(0.f, 0.f, 0.f, 0.f);
            const float4* ar = (const float4*)(ab + (size_t)node[i] * Kn);
            a0[i] = ar[0]; a1[i] = ar[1];
        }
#pragma unroll
        for (int i = 0; i < 4; i++) {
            float w[9] = {a0[i].x, a0[i].y, a0[i].z, a0[i].w,
                          a1[i].x, a1[i].y, a1[i].z, a1[i].w, 1.0f};
#pragma unroll
            for (int k = 0; k < 9; k++) {
                acc[k].x += w[k] * v[i].x;
                acc[k].y += w[k] * v[i].y;
                acc[k].z += w[k] * v[i].z;
                acc[k].w += w[k] * v[i].w;
            }
        }
    }
    // merge odd-node half into even half (same d-range)
#pragma unroll
    for (int k = 0; k < 9; k++) {
        acc[k].x += __shfl_down(acc[k].x, 32, 64);
        acc[k].y += __shfl_down(acc[k].y, 32, 64);
        acc[k].z += __shfl_down(acc[k].z, 32, 64);
        acc[k].w += __shfl_down(acc[k].w, 32, 64);
    }
    if (half == 0) {
#pragma unroll
        for (int k = 0; k < 9; k++)
            ((float4*)red[wv][k])[dl] = acc[k];
    }
    __syncthreads();
    // cross-wave reduce 8->1: threads 0..287 each own one (k, d4) float4 slot
    int slot = threadIdx.x;
    if (slot < 9 * (Dn / 4)) {
        int k = slot >> 5, d4 = slot & 31;
        float4 t = make_float4(0.f, 0.f, 0.f, 0.f);
#pragma unroll
        for (int w = 0; w < 8; w++) {
            float4 v = ((const float4*)red[w][k])[d4];
            t.x += v.x; t.y += v.y; t.z += v.z; t.w += v.w;
        }
        float4* gp = (float4*)(partial + (((size_t)b * 9 + k) * GBLK + blockIdx.y) * Dn);
        gp[d4] = t;
    }
}

// K4: one block per (graph, matrix m). Reduce over 16 block-slabs is a
// CONTIGUOUS 8 KB float4 stream ([m] slab of partial). Then matvec -> gmat.
__global__ __launch_bounds__(256) void matvec_kernel(const float* __restrict__ partial,
                                                     const float* __restrict__ root,
                                                     const float* __restrict__ bases,
                                                     float* __restrict__ gmat) {
    int b = blockIdx.x, m = blockIdx.y;
    int tid = threadIdx.x;
    __shared__ float4 ts4[Dn / 4];                // ts[128] as 32 float4
    __shared__ float tsh[8][Dn];
    int dg = tid & 31, part = tid >> 5;           // 32 d-groups x 8 parts
    const float4* p4 = (const float4*)(partial + ((size_t)b * 9 + m) * GBLK * Dn);
    float4 sum = make_float4(0.f, 0.f, 0.f, 0.f);
    for (int c = part; c < GBLK; c += 8) {        // 2 iters, contiguous stream
        float4 v = p4[c * 32 + dg];
        sum.x += v.x; sum.y += v.y; sum.z += v.z; sum.w += v.w;
    }
    ((float4*)tsh[part])[dg] = sum;
    __syncthreads();
    if (part == 0) {
        float4 t = make_float4(0.f, 0.f, 0.f, 0.f);
#pragma unroll
        for (int r = 0; r < 8; r++) {
            float4 v = ((float4*)tsh[r])[dg];
            t.x += v.x; t.y += v.y; t.z += v.z; t.w += v.w;
        }
        ts4[dg] = t;
    }
    __syncthreads();
    const float* ts = (const float*)ts4;
    const float* M  = (m == 8) ? root : bases + (size_t)m * Dn * Dn;
    int d = tid & (Dn - 1), h = tid >> 7;
    float g = 0.0f;
#pragma unroll 8
    for (int j = h * 64; j < h * 64 + 64; j++) g += ts[j] * M[j * Dn + d];
    __syncthreads();
    tsh[h][d] = g;
    __syncthreads();
    if (h == 0) gmat[((size_t)b * 9 + m) * Dn + d] = tsh[0][d] + tsh[1][d];
}

// K5: sum the 9 matvec outputs, add bias term, L2-normalize.
__global__ __launch_bounds__(128) void norm_kernel(const float* __restrict__ gmat,
                                                   const float* __restrict__ bias,
                                                   float* __restrict__ out) {
    int b = blockIdx.x, d = threadIdx.x;
    float g = (float)Nn * bias[d];
    const float* gb = gmat + (size_t)b * 9 * Dn + d;
#pragma unroll
    for (int m = 0; m < 9; m++) g += gb[m * Dn];
    float ss = g * g;
#pragma unroll
    for (int off = 32; off > 0; off >>= 1) ss += __shfl_down(ss, off, 64);
    __shared__ float s2[2];
    if ((threadIdx.x & 63) == 0) s2[threadIdx.x >> 6] = ss;
    __syncthreads();
    float nrm = sqrtf(s2[0] + s2[1]);
    out[b * Dn + d] = g / fmaxf(nrm, 1e-5f);
}

extern "C" void kernel_launch(void* const* d_in, const int* in_sizes, int n_in,
                              void* d_out, int out_size, void* d_ws, size_t ws_size,
                              hipStream_t stream) {
    const int*   node_ids   = (const int*)d_in[0];
    const int*   edge_index = (const int*)d_in[1];
    const int*   edge_type  = (const int*)d_in[2];
    const float* embedding  = (const float*)d_in[3];
    const float* bases      = (const float*)d_in[4];
    const float* comp       = (const float*)d_in[5];
    const float* root       = (const float*)d_in[6];
    const float* bias       = (const float*)d_in[7];
    float*       out        = (float*)d_out;

    char* w = (char*)d_ws;
    float* inv     = (float*)(w + 0);
    float* a       = (float*)(w + 4096000);
    float* partial = (float*)(w + 6144000);
    float* gmat    = (float*)(w + 8503296);

    cntinv_kernel<<<dim3(Bn, SUBS), 1024, 0, stream>>>(edge_index, edge_type, inv);
    a_kernel     <<<dim3(Bn, SUBS), 1024, 0, stream>>>(edge_index, edge_type, inv, comp, a);
    gather_kernel<<<dim3(Bn, GBLK), 512,  0, stream>>>(node_ids, embedding, a, partial);
    matvec_kernel<<<dim3(Bn, 9),    256,  0, stream>>>(partial, root, bases, gmat);
    norm_kernel  <<<Bn, 128, 0, stream>>>(gmat, bias, out);
}